// Round 1
// baseline (60.916 us; speedup 1.0000x reference)
//
#include <hip/hip_runtime.h>

// Problem constants (from reference): B=4096, N=128, T=64, R=16, D=128.
// out[b,n,:] = tables[template_id[b], atom_role[b,n], :]   (all fp32)
// Traffic: 256 MiB write (dominant), ~2.5 MB effective read -> memory-bound.

constexpr int B = 4096;
constexpr int N = 128;
constexpr int R = 16;
constexpr int D = 128;
constexpr int F4_PER_ROW = D / 4;          // 32 float4 per output row
constexpr int TOTAL_F4   = B * N * F4_PER_ROW;  // 16,777,216

__global__ __launch_bounds__(256) void role_embed_gather(
    const int* __restrict__ template_id,   // [B]
    const int* __restrict__ atom_role,     // [B*N]
    const float* __restrict__ tables,      // [T*R*D]
    float4* __restrict__ out)              // [B*N*D/4]
{
    int idx = blockIdx.x * blockDim.x + threadIdx.x;
    const int stride = gridDim.x * blockDim.x;
    for (; idx < TOTAL_F4; idx += stride) {
        const int row = idx >> 5;          // which (b,n) row (F4_PER_ROW=32)
        const int c4  = idx & 31;          // float4 column within the row
        const int b   = row >> 7;          // N = 128
        const int t   = template_id[b];    // broadcast within 32-lane group (L1 hit)
        const int r   = atom_role[row];    // broadcast within 32-lane group (L1 hit)
        // tables fits in 512 KB -> resident in each XCD L2 after first touch
        const float4 v = *reinterpret_cast<const float4*>(
            &tables[(t * R + r) * D + (c4 << 2)]);
        out[idx] = v;
    }
}

extern "C" void kernel_launch(void* const* d_in, const int* in_sizes, int n_in,
                              void* d_out, int out_size, void* d_ws, size_t ws_size,
                              hipStream_t stream) {
    const int*   template_id = (const int*)d_in[0];
    const int*   atom_role   = (const int*)d_in[1];
    const float* tables      = (const float*)d_in[2];
    float4*      out         = (float4*)d_out;

    // Memory-bound: cap grid at ~2048 blocks (256 CU x 8) and grid-stride.
    const int block = 256;
    const int grid  = 2048;
    role_embed_gather<<<grid, block, 0, stream>>>(template_id, atom_role, tables, out);
}

// Round 3
// 53.278 us; speedup vs baseline: 1.1434x; 1.1434x over previous
//
#include <hip/hip_runtime.h>

// out[b,n,:] = tables[template_id[b], atom_role[b,n], :]   (all fp32)
// B=4096, N=128, T=64, R=16, D=128.
// 256 MiB streaming write (dominant) + ~2.5 MB cached reads -> write-BW-bound.
// Floor: ~268 MB / 7.1 TB/s (measured fill-kernel write ceiling) ~= 38 us.

constexpr int B = 4096;
constexpr int N = 128;
constexpr int R = 16;
constexpr int D = 128;
constexpr int F4_PER_ROW = D / 4;                 // 32 float4 per output row
constexpr int TOTAL_F4   = B * N * F4_PER_ROW;    // 16,777,216
constexpr int UNROLL     = 8;
constexpr int BLOCK      = 256;
constexpr int GRID       = TOTAL_F4 / (BLOCK * UNROLL);  // 8192, exact

// Native clang vector type: accepted by __builtin_nontemporal_store
// (HIP's float4 struct is not).
typedef float floatx4 __attribute__((ext_vector_type(4)));

__global__ __launch_bounds__(BLOCK) void role_embed_gather(
    const int* __restrict__ template_id,   // [B]
    const int* __restrict__ atom_role,     // [B*N]
    const float* __restrict__ tables,      // [T*R*D]
    floatx4* __restrict__ out)             // [B*N*D/4]
{
    const int base = blockIdx.x * (BLOCK * UNROLL) + threadIdx.x;

    // Phase 1: all index loads issued back-to-back (independent, L1/L2-hit).
    int t[UNROLL], r[UNROLL];
#pragma unroll
    for (int k = 0; k < UNROLL; ++k) {
        const int e   = base + k * BLOCK;
        const int row = e >> 5;            // (b,n) row;  F4_PER_ROW = 32
        t[k] = template_id[row >> 7];      // N = 128
        r[k] = atom_role[row];
    }

    // Phase 2: 8 independent table loads (512 KB table -> L2-resident).
    floatx4 v[UNROLL];
#pragma unroll
    for (int k = 0; k < UNROLL; ++k) {
        const int e  = base + k * BLOCK;
        const int c4 = e & 31;
        v[k] = *reinterpret_cast<const floatx4*>(
            &tables[(t[k] * R + r[k]) * D + (c4 << 2)]);
    }

    // Phase 3: coalesced non-temporal stores (don't thrash tables out of L2).
#pragma unroll
    for (int k = 0; k < UNROLL; ++k) {
        const int e = base + k * BLOCK;
        __builtin_nontemporal_store(v[k], &out[e]);
    }
}

extern "C" void kernel_launch(void* const* d_in, const int* in_sizes, int n_in,
                              void* d_out, int out_size, void* d_ws, size_t ws_size,
                              hipStream_t stream) {
    const int*   template_id = (const int*)d_in[0];
    const int*   atom_role   = (const int*)d_in[1];
    const float* tables      = (const float*)d_in[2];
    floatx4*     out         = (floatx4*)d_out;

    role_embed_gather<<<GRID, BLOCK, 0, stream>>>(template_id, atom_role, tables, out);
}